// Round 4
// baseline (121.282 us; speedup 1.0000x reference)
//
#include <hip/hip_runtime.h>
#include <math.h>

#define N1 16384
#define N2 16384
#define BLOCK 256
#define PTS 16                         // pos1 points per thread
#define I_BLOCKS (N1 / (BLOCK * PTS))  // 4 blocks along pos1
#define SLICES 256                     // pos2 slices (grid.y) -> 1024 blocks total

// Stage 1: partial min over one pos2 slice of g(q) = -2 p.q + |q|^2
// (d^2 = |p|^2 + g; the |p|^2 shift is applied in stage 2).
// No LDS: q is wave-uniform -> compiler promotes pos2[.] to scalar loads
// (s_load_dwordx2), leaving the LDS unit idle and the VALU pipe as the
// only consumer. The (-2qx,-2qy,|q|^2) transform is 3 VALU ops per j,
// amortized over PTS=16 (48 ops).
__global__ __launch_bounds__(BLOCK, 4)
void nn_partial(const float2* __restrict__ pos1,
                const float2* __restrict__ pos2,
                float* __restrict__ partials,
                unsigned int* __restrict__ ticket,
                int slice_n) {
    const int ib = blockIdx.x;
    const int sl = blockIdx.y;
    const int t  = threadIdx.x;

    if (ib == 0 && sl == 0 && t == 0) *ticket = 0;  // init for stage 2

    const float2* __restrict__ q = pos2 + (size_t)sl * slice_n;

    const int i0 = ib * (BLOCK * PTS) + t;
    float x[PTS], y[PTS], m[PTS];
#pragma unroll
    for (int k = 0; k < PTS; ++k) {
        float2 p = pos1[i0 + k * BLOCK];
        x[k] = p.x;
        y[k] = p.y;
        m[k] = 3.4e38f;
    }

#pragma unroll 4
    for (int j = 0; j < slice_n; ++j) {
        float2 qj = q[j];              // uniform address -> scalar load
        float qx = -2.f * qj.x;
        float qy = -2.f * qj.y;
        float qz = fmaf(qj.x, qj.x, qj.y * qj.y);
#pragma unroll
        for (int k = 0; k < PTS; ++k) {
            m[k] = fminf(m[k], fmaf(x[k], qx, fmaf(y[k], qy, qz)));
        }
    }

#pragma unroll
    for (int k = 0; k < PTS; ++k) {
        partials[(size_t)sl * N1 + i0 + k * BLOCK] = m[k];
    }
}

// Stage 2 (fused final): 64 blocks; each thread owns one pos1 point.
// Min over slices (coalesced), + |p|^2, sqrt, block-sum; last block (ticket)
// reduces the 64 block sums and writes the mean.
__global__ __launch_bounds__(BLOCK)
void nn_reduce(const float* __restrict__ partials,
               const float2* __restrict__ pos1,
               float* __restrict__ blocksums,
               unsigned int* __restrict__ ticket,
               float* __restrict__ out,
               int slices) {
    const int t = threadIdx.x;
    const int i = blockIdx.x * BLOCK + t;

    float m = 3.4e38f;
#pragma unroll 8
    for (int s = 0; s < slices; ++s) {
        m = fminf(m, partials[(size_t)s * N1 + i]);
    }
    float2 p = pos1[i];
    float d2 = fmaxf(fmaf(p.x, p.x, p.y * p.y) + m, 0.f);
    float sum = sqrtf(d2);

    for (int off = 32; off > 0; off >>= 1) {
        sum += __shfl_down(sum, off, 64);
    }
    __shared__ float wsum[BLOCK / 64];
    __shared__ int lastflag;
    if ((t & 63) == 0) wsum[t >> 6] = sum;
    __syncthreads();
    if (t == 0) {
        float s = 0.f;
        for (int w = 0; w < BLOCK / 64; ++w) s += wsum[w];
        blocksums[blockIdx.x] = s;
        __threadfence();
        unsigned int old = atomicAdd(ticket, 1u);
        lastflag = (old == gridDim.x - 1) ? 1 : 0;
    }
    __syncthreads();
    if (lastflag && t < 64) {
        volatile float* vb = (volatile float*)blocksums;
        float v = vb[t];
        for (int off = 32; off > 0; off >>= 1) {
            v += __shfl_down(v, off, 64);
        }
        if (t == 0) out[0] = v / (float)N1;
    }
}

extern "C" void kernel_launch(void* const* d_in, const int* in_sizes, int n_in,
                              void* d_out, int out_size, void* d_ws, size_t ws_size,
                              hipStream_t stream) {
    const float2* pos1 = (const float2*)d_in[0];
    const float2* pos2 = (const float2*)d_in[1];
    float* out = (float*)d_out;
    float* partials = (float*)d_ws;

    const int nblk2 = N1 / BLOCK;  // 64
    // 256 slices -> 16 MB partials; degrade if ws is smaller (no LDS cap now).
    int slices = SLICES;
    while (slices > 1 &&
           (size_t)slices * N1 * sizeof(float) + (nblk2 + 1) * sizeof(float) > ws_size)
        slices >>= 1;
    const int slice_n = N2 / slices;

    float* blocksums = partials + (size_t)slices * N1;
    unsigned int* ticket = (unsigned int*)(blocksums + nblk2);

    dim3 grid1(I_BLOCKS, slices);
    nn_partial<<<grid1, BLOCK, 0, stream>>>(pos1, pos2, partials, ticket, slice_n);
    nn_reduce<<<nblk2, BLOCK, 0, stream>>>(partials, pos1, blocksums, ticket, out, slices);
}

// Round 5
// 78.122 us; speedup vs baseline: 1.5525x; 1.5525x over previous
//
#include <hip/hip_runtime.h>
#include <math.h>

#define N1 16384
#define N2 16384
#define BLOCK 256
#define PTS 8                          // pos1 points per thread
#define I_BLOCKS (N1 / (BLOCK * PTS))  // 8 blocks along pos1
#define SLICES 128                     // pos2 slices -> 1024 blocks, 4 waves/SIMD

// order-preserving float<->uint mapping (for atomicMin over possibly-negative g)
__device__ __forceinline__ unsigned int f2key(float f) {
    unsigned int b = __float_as_uint(f);
    return (b & 0x80000000u) ? ~b : (b | 0x80000000u);
}
__device__ __forceinline__ float key2f(unsigned int k) {
    unsigned int b = (k & 0x80000000u) ? (k & 0x7FFFFFFFu) : ~k;
    return __uint_as_float(b);
}

// Stage 1: for each pos1 point, min over one pos2 slice of
// g(q) = -2 p.q + |q|^2  (d^2 = |p|^2 + g, shift applied in stage 2).
// pos2 is read as uniform float4 (2 points / 16B load, L1-resident slice).
// Cross-slice combine is a fire-and-forget device-scope atomicMin on a
// 64 KB key array -- no 16 MB partials round-trip.
__global__ __launch_bounds__(BLOCK, 4)
void nn_partial(const float2* __restrict__ pos1,
                const float4* __restrict__ pos2,   // 2 points per float4
                unsigned int* __restrict__ keys,
                unsigned int* __restrict__ ticket,
                int slice_f4) {
    const int ib = blockIdx.x;
    const int sl = blockIdx.y;
    const int t  = threadIdx.x;

    if (ib == 0 && sl == 0 && t == 0) *ticket = 0;  // init for stage 2

    const float4* __restrict__ q = pos2 + (size_t)sl * slice_f4;
    const int i0 = ib * (BLOCK * PTS) + t;

    float x[PTS], y[PTS], m[PTS];
#pragma unroll
    for (int k = 0; k < PTS; ++k) {
        float2 p = pos1[i0 + k * BLOCK];
        x[k] = p.x; y[k] = p.y; m[k] = 3.4e38f;
    }

#pragma unroll 4
    for (int j = 0; j < slice_f4; ++j) {
        float4 qq = q[j];                       // uniform address, 2 pos2 points
        float ax = -2.f * qq.x, ay = -2.f * qq.y;
        float az = fmaf(qq.x, qq.x, qq.y * qq.y);
        float bx = -2.f * qq.z, by = -2.f * qq.w;
        float bz = fmaf(qq.z, qq.z, qq.w * qq.w);
#pragma unroll
        for (int k = 0; k < PTS; ++k) {
            m[k] = fminf(m[k], fmaf(x[k], ax, fmaf(y[k], ay, az)));
            m[k] = fminf(m[k], fmaf(x[k], bx, fmaf(y[k], by, bz)));
        }
    }

#pragma unroll
    for (int k = 0; k < PTS; ++k) {
        atomicMin(&keys[i0 + k * BLOCK], f2key(m[k]));  // fire-and-forget
    }
}

// Stage 2 (fused final): 64 blocks; decode key, + |p|^2, sqrt, block-sum;
// last block (ticket) reduces the 64 block sums and writes the mean.
__global__ __launch_bounds__(BLOCK)
void nn_finish(const unsigned int* __restrict__ keys,
               const float2* __restrict__ pos1,
               float* __restrict__ blocksums,
               unsigned int* __restrict__ ticket,
               float* __restrict__ out) {
    const int t = threadIdx.x;
    const int i = blockIdx.x * BLOCK + t;

    float g = key2f(keys[i]);
    float2 p = pos1[i];
    float d2 = fmaxf(fmaf(p.x, p.x, p.y * p.y) + g, 0.f);
    float sum = sqrtf(d2);

    for (int off = 32; off > 0; off >>= 1) {
        sum += __shfl_down(sum, off, 64);
    }
    __shared__ float wsum[BLOCK / 64];
    __shared__ int lastflag;
    if ((t & 63) == 0) wsum[t >> 6] = sum;
    __syncthreads();
    if (t == 0) {
        float s = 0.f;
        for (int w = 0; w < BLOCK / 64; ++w) s += wsum[w];
        blocksums[blockIdx.x] = s;
        __threadfence();
        unsigned int old = atomicAdd(ticket, 1u);
        lastflag = (old == gridDim.x - 1) ? 1 : 0;
    }
    __syncthreads();
    if (lastflag && t < 64) {
        volatile float* vb = (volatile float*)blocksums;
        float v = vb[t];
        for (int off = 32; off > 0; off >>= 1) {
            v += __shfl_down(v, off, 64);
        }
        if (t == 0) out[0] = v / (float)N1;
    }
}

extern "C" void kernel_launch(void* const* d_in, const int* in_sizes, int n_in,
                              void* d_out, int out_size, void* d_ws, size_t ws_size,
                              hipStream_t stream) {
    const float2* pos1 = (const float2*)d_in[0];
    const float4* pos2 = (const float4*)d_in[1];
    float* out = (float*)d_out;

    unsigned int* keys = (unsigned int*)d_ws;               // N1 uints (64 KB)
    float* blocksums   = (float*)(keys + N1);               // 64 floats
    unsigned int* ticket = (unsigned int*)(blocksums + 64); // 1 uint

    const int slice_f4 = (N2 / SLICES) / 2;  // float4s per slice (64)

    // init keys to +inf ordering (0xFFFFFFFF)
    hipMemsetAsync(keys, 0xFF, (size_t)N1 * sizeof(unsigned int), stream);

    dim3 grid1(I_BLOCKS, SLICES);
    nn_partial<<<grid1, BLOCK, 0, stream>>>(pos1, pos2, keys, ticket, slice_f4);
    nn_finish<<<N1 / BLOCK, BLOCK, 0, stream>>>(keys, pos1, blocksums, ticket, out);
}